// Round 16
// baseline (255.343 us; speedup 1.0000x reference)
//
#include <hip/hip_runtime.h>
#include <hip/hip_bf16.h>

#define BB 256
#define LL 200
#define CC 4
#define HH 128
#define G3 384

typedef short bf16x8 __attribute__((ext_vector_type(8)));
typedef float f32x4 __attribute__((ext_vector_type(4)));

#define MFMA16(a, b, c) __builtin_amdgcn_mfma_f32_16x16x32_bf16((a), (b), (c), 0, 0, 0)

__device__ __forceinline__ short bf16_rne(float x) {
    union { float f; unsigned u; } v; v.f = x;
    unsigned r = v.u + 0x7FFFu + ((v.u >> 16) & 1u);
    return (short)(r >> 16);
}
__device__ __forceinline__ float rcp_(float x) { return __builtin_amdgcn_rcpf(x); }
__device__ __forceinline__ float sigm_(float x) { return rcp_(1.0f + __expf(-x)); }
__device__ __forceinline__ float tanhf_(float x) { return 2.0f * rcp_(1.0f + __expf(-2.0f * x)) - 1.0f; }

__device__ __forceinline__ uint2 pack4(float4 v) {
    uint2 p;
    p.x = (unsigned)(unsigned short)bf16_rne(v.x) | ((unsigned)(unsigned short)bf16_rne(v.y) << 16);
    p.y = (unsigned)(unsigned short)bf16_rne(v.z) | ((unsigned)(unsigned short)bf16_rne(v.w) << 16);
    return p;
}

// ---------------------------------------------------------------------------
// lengths from timeline_mask (bool-dtype detection, verified R1-R15)
// ---------------------------------------------------------------------------
__global__ void compute_lens_kernel(const unsigned char* __restrict__ mask8,
                                    int* __restrict__ lens) {
    __shared__ int bad;
    int b = threadIdx.x;
    if (b == 0) bad = 0;
    __syncthreads();
    int cnt8 = 0, prev = 0, mono = 1;
    for (int t = 0; t < LL; ++t) {
        int v = mask8[b * LL + t] ? 1 : 0;
        cnt8 += (v == 0);
        if (v < prev) mono = 0;
        prev = v;
    }
    if (!mono) atomicAdd(&bad, 1);
    __syncthreads();
    int len;
    if (bad == 0) {
        len = cnt8;
    } else {
        const int* m32 = (const int*)mask8;
        int c = 0;
        for (int t = 0; t < LL; ++t) c += (m32[b * LL + t] == 0);
        len = c;
    }
    if (len < 1) len = 1;
    if (len > LL) len = LL;
    lens[b] = len;
}

// ---------------------------------------------------------------------------
// weight split: bf16 hi for W_ih and W_hh
// ---------------------------------------------------------------------------
__global__ void wsplit_kernel(const float* __restrict__ Wih, const float* __restrict__ Whh,
                              short* __restrict__ wih_hi, short* __restrict__ whh_hi) {
    int i = blockIdx.x * 256 + threadIdx.x;   // 768 blocks -> 196608
    wih_hi[i] = bf16_rne(Wih[i]);
    whh_hi[i] = bf16_rne(Whh[i]);
}

// ---------------------------------------------------------------------------
// presplit: pre-roll + bf16-convert + A-frag-order x into global ws.
// Per (c,bt,s): 64 lanes x 32 shorts (4 KB). Lane l holds element
// [row=l&15][k = ks*32 + (l>>4)*8 + j], ks=0..3, j=0..7 -> lane-contiguous
// 64 B, so the fused kernel reads its frags with 4x global_load_dwordx4.
// ---------------------------------------------------------------------------
__global__ __launch_bounds__(256) void presplit_kernel(
    const float* __restrict__ seqs, const int* __restrict__ lens,
    short* __restrict__ xsplit)
{
    const int qx = blockIdx.x;         // 0..49
    const int bt = blockIdx.y;         // 0..15
    const int c  = blockIdx.z;         // 0..3
    const int f = threadIdx.x >> 6;    // 0..3
    const int lane = threadIdx.x & 63;
    const int s = qx * 4 + f;
    const int row = lane & 15, gg = lane >> 4;
    const int b = bt * 16 + row;
    const int len = lens[b];
    int tt = s + LL - len; if (tt >= LL) tt -= LL;

    const float* src = seqs + ((size_t)(b * LL + tt) * CC + c) * HH + gg * 8;
    short* dst = xsplit + ((size_t)((c * 16 + bt) * LL + s)) * 2048 + (size_t)lane * 32;

    #pragma unroll
    for (int ks = 0; ks < 4; ++ks) {
        float4 a0 = *(const float4*)(src + ks * 32);
        float4 a1 = *(const float4*)(src + ks * 32 + 4);
        uint2 p0 = pack4(a0), p1 = pack4(a1);
        *(uint4*)(dst + ks * 8) = make_uint4(p0.x, p0.y, p1.x, p1.y);
    }
}

// ---------------------------------------------------------------------------
// Fused GRU: grid (16 bt x 4 c) = 64 WGs, 512 thr = 8 waves = 2 waves/SIMD.
// R16 = R15 (proven 228us) with the x-path hoisted out of the serial loop:
//  - PS=true: x A-frags PRECOMPUTED in global (presplit kernel). Fused loop
//    loads 4x b128/step, prefetched 2 steps ahead into regs. Deletes pack4,
//    the stager, the xs LDS buffers (+their reads/writes/conflicts).
//  - PS=false: R15's in-kernel staging (fallback if ws too small).
// h bf16-only in LDS (R15-proven, absmax unchanged); C-init biases; BH
// AGPR-pinned; one raw barrier/step (lgkm-only drain).
// ---------------------------------------------------------------------------
template<bool PS>
__global__ __launch_bounds__(512, 2) void gru_fused_kernel(
    const float* __restrict__ seqs,    // (B,L,C,H)
    const short* __restrict__ xsplit,  // A-frag-ordered bf16 x (PS only)
    const int*   __restrict__ lens,    // (B,)
    const short* __restrict__ wih_hi,  // (C,384,128) bf16
    const short* __restrict__ whh_hi,  // (C,384,128) bf16
    const float* __restrict__ b_ih,    // (C,384)
    const float* __restrict__ b_hh,    // (C,384)
    float*       __restrict__ out)     // (C,B,L,H)
{
    const int bt = blockIdx.x;             // 0..15
    const int c  = blockIdx.y;             // 0..3
    const int bbase = bt * 16;
    const int tid = threadIdx.x;           // 0..511
    const int w = tid >> 6;                // wave 0..7
    const int l = tid & 63;
    const int l15 = l & 15, g = l >> 4;    // A-row = l15, k-group = g

    __shared__ __align__(16) short hA[2][16][136];   // [buf][batch][k] bf16 h
    __shared__ __align__(16) short xs[2][16][136];   // fallback staging only

    // ---- weight fragments: B-frag row NT*16+l15, k = ks*32 + g*8 + j ----
    bf16x8 BH[3][4], WI[3][4];
    #pragma unroll
    for (int q = 0; q < 3; ++q) {
        const int NT = q * 8 + w;
        #pragma unroll
        for (int ks = 0; ks < 4; ++ks) {
            size_t off = (size_t)(c * G3 + NT * 16 + l15) * HH + ks * 32 + g * 8;
            BH[q][ks] = *(const bf16x8*)(whh_hi + off);
            WI[q][ks] = *(const bf16x8*)(wih_hi + off);
        }
    }
    #pragma unroll
    for (int q = 0; q < 3; ++q)
        asm volatile("" : "+a"(BH[q][0]), "+a"(BH[q][1]), "+a"(BH[q][2]), "+a"(BH[q][3]));

    // ---- biases -> persistent C-init vectors ----
    const int col0 = w * 16 + l15;
    const float bRs = b_hh[c * G3 + col0]       + b_ih[c * G3 + col0];
    const float bZs = b_hh[c * G3 + 128 + col0] + b_ih[c * G3 + 128 + col0];
    const float bHN = b_hh[c * G3 + 256 + col0];
    const float bIN = b_ih[c * G3 + 256 + col0];
    const f32x4 cZZ  = (f32x4){0.f, 0.f, 0.f, 0.f};
    const f32x4 cHN4 = (f32x4){bHN, bHN, bHN, bHN};
    const f32x4 cR4  = (f32x4){bRs, bRs, bRs, bRs};
    const f32x4 cZ4  = (f32x4){bZs, bZs, bZs, bZs};
    const f32x4 cN4  = (f32x4){bIN, bIN, bIN, bIN};

    // ---- per-lane output rows: batches bbase + g*4 + r ----
    int lenr[4], tcur[4];
    #pragma unroll
    for (int r = 0; r < 4; ++r) {
        lenr[r] = lens[bbase + g * 4 + r];
        tcur[r] = LL - lenr[r];
    }
    float hold[4] = { 0.f, 0.f, 0.f, 0.f };

    // ---- zero h buffer 0 ([16][136] = 1088 dwords) ----
    for (int i = tid; i < 1088; i += 512) ((int*)hA[0])[i] = 0;

    // ---- x pipeline state ----
    const short* xfrag = nullptr;
    bf16x8 xh[4], xnx[4];                  // x(si+1) frags ready; x(si+2) in flight
    const float* srow = nullptr;           // fallback
    float4 xraw; int txs = 0, bsl = 0, k0s = 0;
    f32x4 xacc[3];

    if constexpr (PS) {
        xfrag = xsplit + (size_t)((c * 16 + bt) * LL) * 2048 + (size_t)l * 32;
        // x(0) frags -> xacc(0)
        bf16x8 x0[4];
        #pragma unroll
        for (int ks = 0; ks < 4; ++ks) x0[ks] = *(const bf16x8*)(xfrag + ks * 8);
        xacc[0] = MFMA16(x0[0], WI[0][0], cR4);
        xacc[1] = MFMA16(x0[0], WI[1][0], cZ4);
        xacc[2] = MFMA16(x0[0], WI[2][0], cN4);
        #pragma unroll
        for (int ks = 1; ks < 4; ++ks) {
            #pragma unroll
            for (int q = 0; q < 3; ++q)
                xacc[q] = MFMA16(x0[ks], WI[q][ks], xacc[q]);
        }
        // x(1) frags ready; issue x(2)
        #pragma unroll
        for (int ks = 0; ks < 4; ++ks) {
            xh[ks]  = *(const bf16x8*)(xfrag + 2048 + ks * 8);
            xnx[ks] = *(const bf16x8*)(xfrag + 2 * 2048 + ks * 8);
        }
        __syncthreads();   // hA[0] zero visible
    } else {
        bsl = tid >> 5; k0s = (tid & 31) * 4;
        const int bs = bbase + bsl;
        const int lenS = lens[bs];
        srow = seqs + ((size_t)bs * LL * CC + c) * HH + k0s;
        int ts0 = LL - lenS;
        int ts1 = ts0 + 1; if (ts1 >= LL) ts1 -= LL;
        float4 xr0 = *(const float4*)(srow + (size_t)ts0 * (CC * HH));
        float4 xr1 = *(const float4*)(srow + (size_t)ts1 * (CC * HH));
        txs = ts1 + 1; if (txs >= LL) txs -= LL;
        *(uint2*)&xs[0][bsl][k0s] = pack4(xr0);
        *(uint2*)&xs[1][bsl][k0s] = pack4(xr1);
        __syncthreads();
        {
            bf16x8 xh0 = *(const bf16x8*)&xs[0][l15][g * 8];
            xacc[0] = MFMA16(xh0, WI[0][0], cR4);
            xacc[1] = MFMA16(xh0, WI[1][0], cZ4);
            xacc[2] = MFMA16(xh0, WI[2][0], cN4);
            #pragma unroll
            for (int ks = 1; ks < 4; ++ks) {
                bf16x8 xq = *(const bf16x8*)&xs[0][l15][ks * 32 + g * 8];
                #pragma unroll
                for (int q = 0; q < 3; ++q) xacc[q] = MFMA16(xq, WI[q][ks], xacc[q]);
            }
        }
        xraw = *(const float4*)(srow + (size_t)txs * (CC * HH));
        txs = (txs + 1 == LL) ? 0 : txs + 1;
        __syncthreads();
    }

    // =======================  main loop  =======================
    for (int si = 0; si < LL; ++si) {
        const int hb = si & 1, hn = hb ^ 1;

        // 0. re-assert AGPR residency of rec weights
        #pragma unroll
        for (int q = 0; q < 3; ++q)
            asm volatile("" : "+a"(BH[q][0]), "+a"(BH[q][1]), "+a"(BH[q][2]), "+a"(BH[q][3]));

        // 1. rec MFMAs: 12 total, C-init peeled
        f32x4 racc[3];
        {
            bf16x8 ah0 = *(const bf16x8*)&hA[hb][l15][g * 8];
            racc[0] = MFMA16(ah0, BH[0][0], cZZ);
            racc[1] = MFMA16(ah0, BH[1][0], cZZ);
            racc[2] = MFMA16(ah0, BH[2][0], cHN4);
            #pragma unroll
            for (int ks = 1; ks < 4; ++ks) {
                bf16x8 ah = *(const bf16x8*)&hA[hb][l15][ks * 32 + g * 8];
                #pragma unroll
                for (int q = 0; q < 3; ++q) racc[q] = MFMA16(ah, BH[q][ks], racc[q]);
            }
        }

        // 2. gates (xacc = xp(si), biases folded)
        float hnew[4];
        #pragma unroll
        for (int r = 0; r < 4; ++r) {
            float gr = sigm_(racc[0][r] + xacc[0][r]);
            float gz = sigm_(racc[1][r] + xacc[1][r]);
            float gn = tanhf_(xacc[2][r] + gr * racc[2][r]);
            float hv = gn + gz * (hold[r] - gn);
            hnew[r] = hv;
            hold[r] = hv;
        }

        // 3. h -> bf16 -> hA[hn] (ds_writes drain under xproj)
        #pragma unroll
        for (int r = 0; r < 4; ++r)
            hA[hn][g * 4 + r][col0] = bf16_rne(hold[r]);

        // 4. out stores (scatter to t, zero-masked; fire-and-forget)
        #pragma unroll
        for (int r = 0; r < 4; ++r) {
            int t = tcur[r];
            int valid = t < lenr[r];
            out[((size_t)(c * BB + bbase + g * 4 + r) * LL + t) * HH + col0]
                = valid ? hnew[r] : 0.0f;
            tcur[r] = (t + 1 == LL) ? 0 : t + 1;
        }

        // 5. xproj for si+1 (off-chain)
        if constexpr (PS) {
            xacc[0] = MFMA16(xh[0], WI[0][0], cR4);
            xacc[1] = MFMA16(xh[0], WI[1][0], cZ4);
            xacc[2] = MFMA16(xh[0], WI[2][0], cN4);
            #pragma unroll
            for (int ks = 1; ks < 4; ++ks) {
                #pragma unroll
                for (int q = 0; q < 3; ++q)
                    xacc[q] = MFMA16(xh[ks], WI[q][ks], xacc[q]);
            }
            // rotate prefetch: xh <- x(si+2) (vmcnt wait lands here), issue x(si+3)
            int s3 = si + 3; s3 = (s3 < LL) ? s3 : LL - 1;
            #pragma unroll
            for (int ks = 0; ks < 4; ++ks) {
                xh[ks]  = xnx[ks];
                xnx[ks] = *(const bf16x8*)(xfrag + (size_t)s3 * 2048 + ks * 8);
            }
        } else {
            const int hx = hn;   // xs parity tracks hA parity (R15 lineage)
            bf16x8 xh0 = *(const bf16x8*)&xs[hx][l15][g * 8];
            xacc[0] = MFMA16(xh0, WI[0][0], cR4);
            xacc[1] = MFMA16(xh0, WI[1][0], cZ4);
            xacc[2] = MFMA16(xh0, WI[2][0], cN4);
            #pragma unroll
            for (int ks = 1; ks < 4; ++ks) {
                bf16x8 xq = *(const bf16x8*)&xs[hx][l15][ks * 32 + g * 8];
                #pragma unroll
                for (int q = 0; q < 3; ++q) xacc[q] = MFMA16(xq, WI[q][ks], xacc[q]);
            }
            *(uint2*)&xs[hb][bsl][k0s] = pack4(xraw);
            xraw = *(const float4*)(srow + (size_t)txs * (CC * HH));
            txs = (txs + 1 == LL) ? 0 : txs + 1;
        }

        // 6. lgkm-only drain + raw barrier (vmem ops stay in flight)
        asm volatile("s_waitcnt lgkmcnt(0)" ::: "memory");
        __builtin_amdgcn_s_barrier();
        __builtin_amdgcn_sched_barrier(0);
        asm volatile("" ::: "memory");
    }
}

extern "C" void kernel_launch(void* const* d_in, const int* in_sizes, int n_in,
                              void* d_out, int out_size, void* d_ws, size_t ws_size,
                              hipStream_t stream) {
    const float* seqs  = (const float*)d_in[0];
    const unsigned char* tmask = (const unsigned char*)d_in[1];
    // d_in[2] = attention_mask (all false, unused)
    const float* W_ih  = (const float*)d_in[3];
    const float* W_hh  = (const float*)d_in[4];
    const float* b_ih  = (const float*)d_in[5];
    const float* b_hh  = (const float*)d_in[6];
    float* out = (float*)d_out;

    char* ws = (char*)d_ws;
    int*   lens   = (int*)(ws);                       // 1 KB
    short* wih_hi = (short*)(ws + 1024);              // 384 KB
    short* whh_hi = (short*)(ws + 1024 + 393216);     // 384 KB
    short* xsplit = (short*)(ws + 787456);            // 52.4 MB (optional)

    const size_t need_ps = 787456ull + (size_t)CC * 16 * LL * 2048 * 2;  // ~53 MB
    const bool ps = (ws_size >= need_ps);

    compute_lens_kernel<<<1, BB, 0, stream>>>(tmask, lens);
    wsplit_kernel<<<768, 256, 0, stream>>>(W_ih, W_hh, wih_hi, whh_hi);

    if (ps) {
        presplit_kernel<<<dim3(50, 16, CC), 256, 0, stream>>>(seqs, lens, xsplit);
        gru_fused_kernel<true><<<dim3(16, CC), 512, 0, stream>>>(
            seqs, xsplit, lens, wih_hi, whh_hi, b_ih, b_hh, out);
    } else {
        gru_fused_kernel<false><<<dim3(16, CC), 512, 0, stream>>>(
            seqs, nullptr, lens, wih_hi, whh_hi, b_ih, b_hh, out);
    }
}

// Round 17
// 203.625 us; speedup vs baseline: 1.2540x; 1.2540x over previous
//
#include <hip/hip_runtime.h>
#include <hip/hip_bf16.h>

#define BB 256
#define LL 200
#define CC 4
#define HH 128
#define G3 384
#define XPAD 168   // row stride in shorts: 336 B == 21*16 (b128-aligned), 84 banks == 20 mod 32 -> 4-way (b128 floor) instead of 8-way at 136

typedef short bf16x8 __attribute__((ext_vector_type(8)));
typedef float f32x4 __attribute__((ext_vector_type(4)));

#define MFMA16(a, b, c) __builtin_amdgcn_mfma_f32_16x16x32_bf16((a), (b), (c), 0, 0, 0)

__device__ __forceinline__ short bf16_rne(float x) {
    union { float f; unsigned u; } v; v.f = x;
    unsigned r = v.u + 0x7FFFu + ((v.u >> 16) & 1u);
    return (short)(r >> 16);
}
__device__ __forceinline__ float rcp_(float x) { return __builtin_amdgcn_rcpf(x); }
__device__ __forceinline__ float sigm_(float x) { return rcp_(1.0f + __expf(-x)); }
__device__ __forceinline__ float tanhf_(float x) { return 2.0f * rcp_(1.0f + __expf(-2.0f * x)) - 1.0f; }

// packed bf16 conversion: 2 f32 -> 1 u32 (lo = src0), single VALU op each
__device__ __forceinline__ unsigned cvtpk(float lo, float hi) {
    unsigned r;
    asm("v_cvt_pk_bf16_f32 %0, %1, %2" : "=v"(r) : "v"(lo), "v"(hi));
    return r;
}
__device__ __forceinline__ uint2 pack4(float4 v) {
    uint2 p;
    p.x = cvtpk(v.x, v.y);
    p.y = cvtpk(v.z, v.w);
    return p;
}

// ---------------------------------------------------------------------------
// lengths from timeline_mask (bool-dtype detection, verified R1-R16)
// ---------------------------------------------------------------------------
__global__ void compute_lens_kernel(const unsigned char* __restrict__ mask8,
                                    int* __restrict__ lens) {
    __shared__ int bad;
    int b = threadIdx.x;
    if (b == 0) bad = 0;
    __syncthreads();
    int cnt8 = 0, prev = 0, mono = 1;
    for (int t = 0; t < LL; ++t) {
        int v = mask8[b * LL + t] ? 1 : 0;
        cnt8 += (v == 0);
        if (v < prev) mono = 0;
        prev = v;
    }
    if (!mono) atomicAdd(&bad, 1);
    __syncthreads();
    int len;
    if (bad == 0) {
        len = cnt8;
    } else {
        const int* m32 = (const int*)mask8;
        int c = 0;
        for (int t = 0; t < LL; ++t) c += (m32[b * LL + t] == 0);
        len = c;
    }
    if (len < 1) len = 1;
    if (len > LL) len = LL;
    lens[b] = len;
}

// ---------------------------------------------------------------------------
// weight split: bf16 hi for W_ih and W_hh (manual rne: host-independent,
// proven lineage)
// ---------------------------------------------------------------------------
__global__ void wsplit_kernel(const float* __restrict__ Wih, const float* __restrict__ Whh,
                              short* __restrict__ wih_hi, short* __restrict__ whh_hi) {
    int i = blockIdx.x * 256 + threadIdx.x;   // 768 blocks -> 196608
    wih_hi[i] = bf16_rne(Wih[i]);
    whh_hi[i] = bf16_rne(Whh[i]);
}

// ---------------------------------------------------------------------------
// Fused GRU: grid (16 bt x 4 c) = 64 WGs, 512 thr = 8 waves = 2 waves/SIMD.
// R17 = R15 (proven best total 228.6us) + three cuts:
//  - XPAD 136->168: frag ds_read_b128 bank conflicts 8-way -> 4-way (the
//    b128 floor). LDS pipe is per-CU and serializes all 8 waves' 32KB/step.
//  - in-loop AGPR re-assert REMOVED (one-time pin kept): R15/R16 FETCH
//    shows no remat; budget 96 AGPR + ~116 VGPR = 212 <= 256. Sentinel:
//    FETCH_SIZE jump => remat came back.
//  - v_cvt_pk_bf16_f32 packing for x stager and h (T12 primitive):
//    ~16 VALU/thread/step removed.
// h bf16-only in LDS double-buffered; x staged bf16 one step ahead; xproj
// (si+1) during step si; C-init biases; one raw barrier/step (lgkm-only).
// ---------------------------------------------------------------------------
__global__ __launch_bounds__(512, 2) void gru_fused_kernel(
    const float* __restrict__ seqs,    // (B,L,C,H)
    const int*   __restrict__ lens,    // (B,)
    const short* __restrict__ wih_hi,  // (C,384,128) bf16
    const short* __restrict__ whh_hi,  // (C,384,128) bf16
    const float* __restrict__ b_ih,    // (C,384)
    const float* __restrict__ b_hh,    // (C,384)
    float*       __restrict__ out)     // (C,B,L,H)
{
    const int bt = blockIdx.x;             // 0..15
    const int c  = blockIdx.y;             // 0..3
    const int bbase = bt * 16;
    const int tid = threadIdx.x;           // 0..511
    const int w = tid >> 6;                // wave 0..7
    const int l = tid & 63;
    const int l15 = l & 15, g = l >> 4;    // A-row = l15, k-group = g

    __shared__ __align__(16) short hA[2][16][XPAD];   // [buf][batch][k] bf16 h
    __shared__ __align__(16) short xs[2][16][XPAD];   // [buf][batch][k] bf16 x

    // ---- weight fragments: B-frag row NT*16+l15, k = ks*32 + g*8 + j ----
    bf16x8 BH[3][4], WI[3][4];
    #pragma unroll
    for (int q = 0; q < 3; ++q) {
        const int NT = q * 8 + w;
        #pragma unroll
        for (int ks = 0; ks < 4; ++ks) {
            size_t off = (size_t)(c * G3 + NT * 16 + l15) * HH + ks * 32 + g * 8;
            BH[q][ks] = *(const bf16x8*)(whh_hi + off);
            WI[q][ks] = *(const bf16x8*)(wih_hi + off);
        }
    }
    // one-time AGPR pin of rec weights (no in-loop re-assert: R16 FETCH
    // proves no remat at this register pressure)
    #pragma unroll
    for (int q = 0; q < 3; ++q)
        asm volatile("" : "+a"(BH[q][0]), "+a"(BH[q][1]), "+a"(BH[q][2]), "+a"(BH[q][3]));

    // ---- stager: thread stages batch row tid>>5, 4 floats ----
    const int bsl = tid >> 5;               // 0..15
    const int bs  = bbase + bsl;
    const int k0s = (tid & 31) * 4;         // 0..124
    const int lenS = lens[bs];
    const float* srow = seqs + ((size_t)bs * LL * CC + c) * HH + k0s;
    int ts0 = LL - lenS;
    int ts1 = ts0 + 1; if (ts1 >= LL) ts1 -= LL;
    float4 xr0 = *(const float4*)(srow + (size_t)ts0 * (CC * HH));
    float4 xr1 = *(const float4*)(srow + (size_t)ts1 * (CC * HH));
    int txs = ts1 + 1; if (txs >= LL) txs -= LL;   // t for s=2

    // ---- biases -> persistent C-init vectors ----
    const int col0 = w * 16 + l15;
    const float bRs = b_hh[c * G3 + col0]       + b_ih[c * G3 + col0];
    const float bZs = b_hh[c * G3 + 128 + col0] + b_ih[c * G3 + 128 + col0];
    const float bHN = b_hh[c * G3 + 256 + col0];
    const float bIN = b_ih[c * G3 + 256 + col0];
    const f32x4 cZZ  = (f32x4){0.f, 0.f, 0.f, 0.f};
    const f32x4 cHN4 = (f32x4){bHN, bHN, bHN, bHN};
    const f32x4 cR4  = (f32x4){bRs, bRs, bRs, bRs};
    const f32x4 cZ4  = (f32x4){bZs, bZs, bZs, bZs};
    const f32x4 cN4  = (f32x4){bIN, bIN, bIN, bIN};

    // ---- per-lane output rows: batches bbase + g*4 + r ----
    int lenr[4], tcur[4];
    #pragma unroll
    for (int r = 0; r < 4; ++r) {
        lenr[r] = lens[bbase + g * 4 + r];
        tcur[r] = LL - lenr[r];
    }
    float hold[4] = { 0.f, 0.f, 0.f, 0.f };

    // ---- zero h buffer 0 ([16][168] = 1344 dwords) ----
    for (int i = tid; i < 16 * XPAD / 2; i += 512) ((int*)hA[0])[i] = 0;

    // ---- stage x(0)->xs[0], x(1)->xs[1] ----
    *(uint2*)&xs[0][bsl][k0s] = pack4(xr0);
    *(uint2*)&xs[1][bsl][k0s] = pack4(xr1);
    __syncthreads();

    // ---- xacc(0) from xs[0] (C-init peeled) ----
    f32x4 xacc[3];
    {
        bf16x8 xh0 = *(const bf16x8*)&xs[0][l15][g * 8];
        xacc[0] = MFMA16(xh0, WI[0][0], cR4);
        xacc[1] = MFMA16(xh0, WI[1][0], cZ4);
        xacc[2] = MFMA16(xh0, WI[2][0], cN4);
        #pragma unroll
        for (int ks = 1; ks < 4; ++ks) {
            bf16x8 xh = *(const bf16x8*)&xs[0][l15][ks * 32 + g * 8];
            #pragma unroll
            for (int q = 0; q < 3; ++q)
                xacc[q] = MFMA16(xh, WI[q][ks], xacc[q]);
        }
    }
    // issue x(2)
    float4 xraw = *(const float4*)(srow + (size_t)txs * (CC * HH));
    txs = (txs + 1 == LL) ? 0 : txs + 1;

    __syncthreads();   // protect xs[0] from step-0 overwrite

    // =======================  main loop  =======================
    for (int si = 0; si < LL; ++si) {
        const int hb = si & 1, hn = hb ^ 1;

        // 1. rec MFMAs: 12 total, C-init peeled
        f32x4 racc[3];
        {
            bf16x8 ah0 = *(const bf16x8*)&hA[hb][l15][g * 8];
            racc[0] = MFMA16(ah0, BH[0][0], cZZ);
            racc[1] = MFMA16(ah0, BH[1][0], cZZ);
            racc[2] = MFMA16(ah0, BH[2][0], cHN4);
            #pragma unroll
            for (int ks = 1; ks < 4; ++ks) {
                bf16x8 ah = *(const bf16x8*)&hA[hb][l15][ks * 32 + g * 8];
                #pragma unroll
                for (int q = 0; q < 3; ++q) racc[q] = MFMA16(ah, BH[q][ks], racc[q]);
            }
        }

        // 2. gates (xacc = xp(si), biases folded)
        float hnew[4];
        #pragma unroll
        for (int r = 0; r < 4; ++r) {
            float gr = sigm_(racc[0][r] + xacc[0][r]);
            float gz = sigm_(racc[1][r] + xacc[1][r]);
            float gn = tanhf_(xacc[2][r] + gr * racc[2][r]);
            float hv = gn + gz * (hold[r] - gn);
            hnew[r] = hv;
            hold[r] = hv;
        }

        // 3. h -> packed bf16 (2x cvt_pk) -> hA[hn] (writes drain under xproj)
        {
            unsigned pk01 = cvtpk(hold[0], hold[1]);
            unsigned pk23 = cvtpk(hold[2], hold[3]);
            hA[hn][g * 4 + 0][col0] = (short)(pk01 & 0xffffu);
            hA[hn][g * 4 + 1][col0] = (short)(pk01 >> 16);
            hA[hn][g * 4 + 2][col0] = (short)(pk23 & 0xffffu);
            hA[hn][g * 4 + 3][col0] = (short)(pk23 >> 16);
        }

        // 4. out stores (scatter to t, zero-masked; fire-and-forget)
        #pragma unroll
        for (int r = 0; r < 4; ++r) {
            int t = tcur[r];
            int valid = t < lenr[r];
            out[((size_t)(c * BB + bbase + g * 4 + r) * LL + t) * HH + col0]
                = valid ? hnew[r] : 0.0f;
            tcur[r] = (t + 1 == LL) ? 0 : t + 1;
        }

        // 5. xproj for si+1 (off-chain; C-init peeled)
        {
            bf16x8 xh0 = *(const bf16x8*)&xs[hn][l15][g * 8];
            xacc[0] = MFMA16(xh0, WI[0][0], cR4);
            xacc[1] = MFMA16(xh0, WI[1][0], cZ4);
            xacc[2] = MFMA16(xh0, WI[2][0], cN4);
            #pragma unroll
            for (int ks = 1; ks < 4; ++ks) {
                bf16x8 xh = *(const bf16x8*)&xs[hn][l15][ks * 32 + g * 8];
                #pragma unroll
                for (int q = 0; q < 3; ++q)
                    xacc[q] = MFMA16(xh, WI[q][ks], xacc[q]);
            }
        }

        // 6. stage x(si+2) -> xs[hb]; 7. issue x(si+3)
        *(uint2*)&xs[hb][bsl][k0s] = pack4(xraw);
        xraw = *(const float4*)(srow + (size_t)txs * (CC * HH));
        txs = (txs + 1 == LL) ? 0 : txs + 1;

        // 8. lgkm-only drain + raw barrier (vmem ops stay in flight)
        asm volatile("s_waitcnt lgkmcnt(0)" ::: "memory");
        __builtin_amdgcn_s_barrier();
        __builtin_amdgcn_sched_barrier(0);
        asm volatile("" ::: "memory");
    }
}

extern "C" void kernel_launch(void* const* d_in, const int* in_sizes, int n_in,
                              void* d_out, int out_size, void* d_ws, size_t ws_size,
                              hipStream_t stream) {
    const float* seqs  = (const float*)d_in[0];
    const unsigned char* tmask = (const unsigned char*)d_in[1];
    // d_in[2] = attention_mask (all false, unused)
    const float* W_ih  = (const float*)d_in[3];
    const float* W_hh  = (const float*)d_in[4];
    const float* b_ih  = (const float*)d_in[5];
    const float* b_hh  = (const float*)d_in[6];
    float* out = (float*)d_out;

    char* ws = (char*)d_ws;
    int*   lens   = (int*)(ws);                       // 1 KB
    short* wih_hi = (short*)(ws + 1024);              // 384 KB
    short* whh_hi = (short*)(ws + 1024 + 393216);     // 384 KB

    compute_lens_kernel<<<1, BB, 0, stream>>>(tmask, lens);
    wsplit_kernel<<<768, 256, 0, stream>>>(W_ih, W_hh, wih_hi, whh_hi);

    gru_fused_kernel<<<dim3(16, CC), 512, 0, stream>>>(
        seqs, lens, wih_hi, whh_hi, b_ih, b_hh, out);
}